// Round 13
// baseline (174.914 us; speedup 1.0000x reference)
//
#include <hip/hip_runtime.h>

// Problem constants
#define BT_TOTAL (32 * 1024)   // B*T = 32768
#define DIM 512                // D
#define NG 8                   // G groups
#define NK 256                 // K codes per group
#define GD 64                  // group dim
#define QB 128                 // queries per block (x2 k-halves = 256 threads)

#define XQ_ELEMS (BT_TOTAL * DIM)          // 16777216
#define LOSS_OFF XQ_ELEMS                  // 16777216
#define IDX_OFF (XQ_ELEMS + 1)             // 16777217

typedef float f32x16 __attribute__((ext_vector_type(16)));
typedef float f32x2  __attribute__((ext_vector_type(2)));

// ---------------------------------------------------------------------------
// Prep: c_sq[g][k] = sum_d cb[g][k][d]^2 (canonical stride-4 order), zero loss
// ---------------------------------------------------------------------------
__global__ void pq_prep(const float* __restrict__ cb,
                        float* __restrict__ csq,
                        float* __restrict__ loss_slot) {
    int i = blockIdx.x * 256 + threadIdx.x;  // 0 .. 2047
    if (i == 0) *loss_slot = 0.0f;
    if (i < NG * NK) {
        const float* row = cb + (size_t)i * GD;
        float a0 = 0.f, a1 = 0.f, a2 = 0.f, a3 = 0.f;
#pragma unroll
        for (int d = 0; d < GD; d += 4) {
            a0 = fmaf(row[d + 0], row[d + 0], a0);
            a1 = fmaf(row[d + 1], row[d + 1], a1);
            a2 = fmaf(row[d + 2], row[d + 2], a2);
            a3 = fmaf(row[d + 3], row[d + 3], a3);
        }
        csq[i] = (a0 + a1) + (a2 + a3);
    }
}

// extract even/odd dim-pairs from a 16-float SGPR tuple (indices all <= 15)
#define E01(tup, j) ((f32x2){tup[4 * (j) + 0], tup[4 * (j) + 1]})
#define E23(tup, j) ((f32x2){tup[4 * (j) + 2], tup[4 * (j) + 3]})

// ---------------------------------------------------------------------------
// Main: 256 threads = 128 queries x 2 k-halves (r10 proven geometry).
// Codes stream through SGPRs (s_load_dwordx16 + tied lgkmcnt(0), proven
// form). Dot product via explicit v_pk_fma_f32 inline asm: 32 packed ops
// replace 64 scalar FMA. Chain pairing = r11 formulation (absmax 0.0).
// x row loaded once as volatile f32x2 (non-rematerializable -> resident).
// ---------------------------------------------------------------------------
__global__ __launch_bounds__(256)
void pq_main(const float* __restrict__ x,
             const float* __restrict__ cb,
             const float* __restrict__ csq,
             float* __restrict__ out) {
    const int g = blockIdx.y;
    const int t = threadIdx.x;
    const int kh = __builtin_amdgcn_readfirstlane(t >> 7);  // wave-uniform 0/1
    const int ql = t & (QB - 1);
    const int q0 = blockIdx.x * QB;
    const int bt = q0 + ql;

    __shared__ float m_d[QB];
    __shared__ int   m_i[QB];
    __shared__ float wsum[4];

    const float* cbg = cb + (size_t)g * NK * GD;
    const float* csqg = csq + g * NK;

    // x row -> 32 resident f32x2 (volatile: cannot be re-materialized)
    const float* xrow = x + (size_t)bt * DIM + g * GD;
    volatile const f32x2* xv = (volatile const f32x2*)xrow;
    f32x2 xa[16], xb[16];
#pragma unroll
    for (int i = 0; i < 16; ++i) {
        xa[i] = xv[2 * i + 0];   // dims 4i, 4i+1
        xb[i] = xv[2 * i + 1];   // dims 4i+2, 4i+3
    }

    // x_sq, canonical stride-4 pattern (bit-matches rounds 1-12)
    float a0 = 0.f, a1 = 0.f, a2 = 0.f, a3 = 0.f;
#pragma unroll
    for (int i = 0; i < 16; ++i) {
        a0 = fmaf(xa[i].x, xa[i].x, a0);
        a1 = fmaf(xa[i].y, xa[i].y, a1);
        a2 = fmaf(xb[i].x, xb[i].x, a2);
        a3 = fmaf(xb[i].y, xb[i].y, a3);
    }
    const float x_sq = (a0 + a1) + (a2 + a3);

    const int kbase = kh << 7;  // 0 or 128, wave-uniform
    float best = 3.402823466e38f;
    int bi = kbase;

#pragma unroll 1
    for (int kk = 0; kk < NK / 2; ++kk) {
        const int k = kbase + kk;
        f32x16 c0, c1, c2, c3;
        float cs;
        const float* ck = cbg + (size_t)k * GD;
        const float* pk = csqg + k;
        // wave-uniform scalar loads: one 256B code row + its c_sq
        asm volatile(
            "s_load_dwordx16 %0, %5, 0x0\n\t"
            "s_load_dwordx16 %1, %5, 0x40\n\t"
            "s_load_dwordx16 %2, %5, 0x80\n\t"
            "s_load_dwordx16 %3, %5, 0xc0\n\t"
            "s_load_dword    %4, %6, 0x0"
            : "=s"(c0), "=s"(c1), "=s"(c2), "=s"(c3), "=s"(cs)
            : "s"(ck), "s"(pk));
        // waitcnt with tied operands (r4/r9/r10 proven form)
        asm volatile("s_waitcnt lgkmcnt(0)"
                     : "+s"(c0), "+s"(c1), "+s"(c2), "+s"(c3), "+s"(cs));

        // packed dot: acc01 = (d0,d1) chains, acc23 = (d2,d3) chains.
        // pk_mul == fma(c,x,0) bit-exact; component order == r11 (absmax 0.0).
        f32x2 p01a, p23a, p01, p23;
        asm("v_pk_mul_f32 %0, %1, %9\n\t"
            "v_pk_fma_f32 %0, %2, %10, %0\n\t"
            "v_pk_fma_f32 %0, %3, %11, %0\n\t"
            "v_pk_fma_f32 %0, %4, %12, %0\n\t"
            "v_pk_fma_f32 %0, %5, %13, %0\n\t"
            "v_pk_fma_f32 %0, %6, %14, %0\n\t"
            "v_pk_fma_f32 %0, %7, %15, %0\n\t"
            "v_pk_fma_f32 %0, %8, %16, %0"
            : "=&v"(p01a)
            : "s"(E01(c0, 0)), "s"(E01(c0, 1)), "s"(E01(c0, 2)), "s"(E01(c0, 3)),
              "s"(E01(c1, 0)), "s"(E01(c1, 1)), "s"(E01(c1, 2)), "s"(E01(c1, 3)),
              "v"(xa[0]), "v"(xa[1]), "v"(xa[2]), "v"(xa[3]),
              "v"(xa[4]), "v"(xa[5]), "v"(xa[6]), "v"(xa[7]));
        asm("v_pk_mul_f32 %0, %1, %9\n\t"
            "v_pk_fma_f32 %0, %2, %10, %0\n\t"
            "v_pk_fma_f32 %0, %3, %11, %0\n\t"
            "v_pk_fma_f32 %0, %4, %12, %0\n\t"
            "v_pk_fma_f32 %0, %5, %13, %0\n\t"
            "v_pk_fma_f32 %0, %6, %14, %0\n\t"
            "v_pk_fma_f32 %0, %7, %15, %0\n\t"
            "v_pk_fma_f32 %0, %8, %16, %0"
            : "=&v"(p23a)
            : "s"(E23(c0, 0)), "s"(E23(c0, 1)), "s"(E23(c0, 2)), "s"(E23(c0, 3)),
              "s"(E23(c1, 0)), "s"(E23(c1, 1)), "s"(E23(c1, 2)), "s"(E23(c1, 3)),
              "v"(xb[0]), "v"(xb[1]), "v"(xb[2]), "v"(xb[3]),
              "v"(xb[4]), "v"(xb[5]), "v"(xb[6]), "v"(xb[7]));
        asm("v_pk_fma_f32 %0, %2, %10, %1\n\t"
            "v_pk_fma_f32 %0, %3, %11, %0\n\t"
            "v_pk_fma_f32 %0, %4, %12, %0\n\t"
            "v_pk_fma_f32 %0, %5, %13, %0\n\t"
            "v_pk_fma_f32 %0, %6, %14, %0\n\t"
            "v_pk_fma_f32 %0, %7, %15, %0\n\t"
            "v_pk_fma_f32 %0, %8, %16, %0\n\t"
            "v_pk_fma_f32 %0, %9, %17, %0"
            : "=&v"(p01)
            : "v"(p01a),
              "s"(E01(c2, 0)), "s"(E01(c2, 1)), "s"(E01(c2, 2)), "s"(E01(c2, 3)),
              "s"(E01(c3, 0)), "s"(E01(c3, 1)), "s"(E01(c3, 2)), "s"(E01(c3, 3)),
              "v"(xa[8]), "v"(xa[9]), "v"(xa[10]), "v"(xa[11]),
              "v"(xa[12]), "v"(xa[13]), "v"(xa[14]), "v"(xa[15]));
        asm("v_pk_fma_f32 %0, %2, %10, %1\n\t"
            "v_pk_fma_f32 %0, %3, %11, %0\n\t"
            "v_pk_fma_f32 %0, %4, %12, %0\n\t"
            "v_pk_fma_f32 %0, %5, %13, %0\n\t"
            "v_pk_fma_f32 %0, %6, %14, %0\n\t"
            "v_pk_fma_f32 %0, %7, %15, %0\n\t"
            "v_pk_fma_f32 %0, %8, %16, %0\n\t"
            "v_pk_fma_f32 %0, %9, %17, %0"
            : "=&v"(p23)
            : "v"(p23a),
              "s"(E23(c2, 0)), "s"(E23(c2, 1)), "s"(E23(c2, 2)), "s"(E23(c2, 3)),
              "s"(E23(c3, 0)), "s"(E23(c3, 1)), "s"(E23(c3, 2)), "s"(E23(c3, 3)),
              "v"(xb[8]), "v"(xb[9]), "v"(xb[10]), "v"(xb[11]),
              "v"(xb[12]), "v"(xb[13]), "v"(xb[14]), "v"(xb[15]));

        float dot = (p01.x + p01.y) + (p23.x + p23.y);
        float dist = (x_sq + cs) - 2.0f * dot;
        if (dist < best) { best = dist; bi = k; }
    }

    // merge the two halves: prefer the lower half on exact ties
    if (kh == 1) { m_d[ql] = best; m_i[ql] = bi; }
    __syncthreads();
    if (kh == 0) {
        float dh = m_d[ql];
        int ih = m_i[ql];
        if (dh < best) { best = dh; bi = ih; }
        m_i[ql] = bi;  // final winner for the epilogue
        out[IDX_OFF + (size_t)bt * NG + g] = (float)bi;
    }
    __syncthreads();

    // ---- epilogue: coalesced x_q writes + loss partial (r10 verbatim) ----
    const int r_off = t >> 4;   // 0..15
    const int c4i = t & 15;     // float4 column
    float s0 = 0.f, s1 = 0.f, s2 = 0.f, s3 = 0.f;
#pragma unroll
    for (int p = 0; p < 8; ++p) {
        const int r = p * 16 + r_off;
        const int code = m_i[r];
        const size_t base = (size_t)(q0 + r) * DIM + g * GD + c4i * 4;
        float4 x4 = *(const float4*)(x + base);
        float4 q4 = *(const float4*)(cbg + (size_t)code * GD + c4i * 4);
        float dx = q4.x - x4.x;
        float dy = q4.y - x4.y;
        float dz = q4.z - x4.z;
        float dw = q4.w - x4.w;
        float4 o;
        o.x = x4.x + dx;
        o.y = x4.y + dy;
        o.z = x4.z + dz;
        o.w = x4.w + dw;
        *(float4*)(out + base) = o;
        s0 = fmaf(dx, dx, s0);
        s1 = fmaf(dy, dy, s1);
        s2 = fmaf(dz, dz, s2);
        s3 = fmaf(dw, dw, s3);
    }
    float part = (s0 + s1) + (s2 + s3);

    // wave reduce (64 lanes)
#pragma unroll
    for (int off = 32; off > 0; off >>= 1) part += __shfl_down(part, off);

    const int lane = t & 63;
    const int wid = t >> 6;
    if (lane == 0) wsum[wid] = part;
    __syncthreads();
    if (t == 0) {
        float bs = (wsum[0] + wsum[1]) + (wsum[2] + wsum[3]);
        // losses = 2 * sum_g mean_{B,T,gd}; divisor = 32768*64 = 2097152
        atomicAdd(out + LOSS_OFF, bs * (2.0f / 2097152.0f));
    }
}

extern "C" void kernel_launch(void* const* d_in, const int* in_sizes, int n_in,
                              void* d_out, int out_size, void* d_ws, size_t ws_size,
                              hipStream_t stream) {
    const float* x = (const float*)d_in[0];
    const float* cb = (const float*)d_in[1];
    float* out = (float*)d_out;
    float* csq = (float*)d_ws;  // 2048 floats = 8 KB scratch

    pq_prep<<<dim3(8), dim3(256), 0, stream>>>(cb, csq, out + LOSS_OFF);

    dim3 grid(BT_TOTAL / QB, NG);   // (256, 8) = 2048 blocks, 8192 waves
    pq_main<<<grid, dim3(256), 0, stream>>>(x, cb, csq, out);
}

// Round 14
// 154.230 us; speedup vs baseline: 1.1341x; 1.1341x over previous
//
#include <hip/hip_runtime.h>

// Problem constants
#define BT_TOTAL (32 * 1024)   // B*T = 32768
#define DIM 512                // D
#define NG 8                   // G groups
#define NK 256                 // K codes per group
#define GD 64                  // group dim
#define QB 256                 // queries per block (2 per thread x 128 slots)

#define XQ_ELEMS (BT_TOTAL * DIM)          // 16777216
#define LOSS_OFF XQ_ELEMS                  // 16777216
#define IDX_OFF (XQ_ELEMS + 1)             // 16777217

typedef float f32x16 __attribute__((ext_vector_type(16)));

// ---------------------------------------------------------------------------
// Prep: c_sq[g][k] = sum_d cb[g][k][d]^2 (canonical stride-4 order), zero loss
// ---------------------------------------------------------------------------
__global__ void pq_prep(const float* __restrict__ cb,
                        float* __restrict__ csq,
                        float* __restrict__ loss_slot) {
    int i = blockIdx.x * 256 + threadIdx.x;  // 0 .. 2047
    if (i == 0) *loss_slot = 0.0f;
    if (i < NG * NK) {
        const float* row = cb + (size_t)i * GD;
        float a0 = 0.f, a1 = 0.f, a2 = 0.f, a3 = 0.f;
#pragma unroll
        for (int d = 0; d < GD; d += 4) {
            a0 = fmaf(row[d + 0], row[d + 0], a0);
            a1 = fmaf(row[d + 1], row[d + 1], a1);
            a2 = fmaf(row[d + 2], row[d + 2], a2);
            a3 = fmaf(row[d + 3], row[d + 3], a3);
        }
        csq[i] = (a0 + a1) + (a2 + a3);
    }
}

// ---------------------------------------------------------------------------
// Main: 256 threads = 128 query-slots x 2 k-halves; EACH THREAD SCORES TWO
// QUERIES (qA = q0+ql, qB = q0+128+ql) against the same streamed code row —
// one 5x s_load + waitcnt now feeds 128 FMA (halves scalar-miss stall and
// overhead per distance). Loop body asm is the r4/r9/r10 hardware-proven
// form (per-iteration s_load_dwordx16 + tied lgkmcnt(0), no loop-carried
// asm). Per-query numerics bit-match the absmax-0.0 rounds.
// ---------------------------------------------------------------------------
__global__ __launch_bounds__(256)
void pq_main(const float* __restrict__ x,
             const float* __restrict__ cb,
             const float* __restrict__ csq,
             float* __restrict__ out) {
    const int g = blockIdx.y;
    const int t = threadIdx.x;
    const int kh = __builtin_amdgcn_readfirstlane(t >> 7);  // wave-uniform 0/1
    const int ql = t & 127;
    const int q0 = blockIdx.x * QB;
    const int btA = q0 + ql;
    const int btB = q0 + 128 + ql;

    __shared__ float m_d[QB];
    __shared__ int   m_i[QB];
    __shared__ float wsum[4];

    const float* cbg = cb + (size_t)g * NK * GD;
    const float* csqg = csq + g * NK;

    // two x rows -> scalar VGPR values (vectorized loads)
    const float* xrowA = x + (size_t)btA * DIM + g * GD;
    const float* xrowB = x + (size_t)btB * DIM + g * GD;
    float xrA[64], xrB[64];
#pragma unroll
    for (int i = 0; i < 16; ++i) {
        float4 v = ((const float4*)xrowA)[i];
        xrA[i * 4 + 0] = v.x; xrA[i * 4 + 1] = v.y;
        xrA[i * 4 + 2] = v.z; xrA[i * 4 + 3] = v.w;
    }
#pragma unroll
    for (int i = 0; i < 16; ++i) {
        float4 v = ((const float4*)xrowB)[i];
        xrB[i * 4 + 0] = v.x; xrB[i * 4 + 1] = v.y;
        xrB[i * 4 + 2] = v.z; xrB[i * 4 + 3] = v.w;
    }

    // x_sq per query, canonical stride-4 pattern (bit-matches rounds 1-13)
    float x_sqA, x_sqB;
    {
        float a0 = 0.f, a1 = 0.f, a2 = 0.f, a3 = 0.f;
#pragma unroll
        for (int i = 0; i < 16; ++i) {
            a0 = fmaf(xrA[i * 4 + 0], xrA[i * 4 + 0], a0);
            a1 = fmaf(xrA[i * 4 + 1], xrA[i * 4 + 1], a1);
            a2 = fmaf(xrA[i * 4 + 2], xrA[i * 4 + 2], a2);
            a3 = fmaf(xrA[i * 4 + 3], xrA[i * 4 + 3], a3);
        }
        x_sqA = (a0 + a1) + (a2 + a3);
        float b0 = 0.f, b1 = 0.f, b2 = 0.f, b3 = 0.f;
#pragma unroll
        for (int i = 0; i < 16; ++i) {
            b0 = fmaf(xrB[i * 4 + 0], xrB[i * 4 + 0], b0);
            b1 = fmaf(xrB[i * 4 + 1], xrB[i * 4 + 1], b1);
            b2 = fmaf(xrB[i * 4 + 2], xrB[i * 4 + 2], b2);
            b3 = fmaf(xrB[i * 4 + 3], xrB[i * 4 + 3], b3);
        }
        x_sqB = (b0 + b1) + (b2 + b3);
    }

    const int kbase = kh << 7;  // 0 or 128, wave-uniform
    float bestA = 3.402823466e38f, bestB = 3.402823466e38f;
    int biA = kbase, biB = kbase;

#pragma unroll 1
    for (int kk = 0; kk < NK / 2; ++kk) {
        const int k = kbase + kk;
        f32x16 c0, c1, c2, c3;
        float cs;
        const float* ck = cbg + (size_t)k * GD;
        const float* pk = csqg + k;
        // wave-uniform scalar loads: one 256B code row + its c_sq
        asm volatile(
            "s_load_dwordx16 %0, %5, 0x0\n\t"
            "s_load_dwordx16 %1, %5, 0x40\n\t"
            "s_load_dwordx16 %2, %5, 0x80\n\t"
            "s_load_dwordx16 %3, %5, 0xc0\n\t"
            "s_load_dword    %4, %6, 0x0"
            : "=s"(c0), "=s"(c1), "=s"(c2), "=s"(c3), "=s"(cs)
            : "s"(ck), "s"(pk));
        // waitcnt with tied operands (r4/r9/r10 proven form)
        asm volatile("s_waitcnt lgkmcnt(0)"
                     : "+s"(c0), "+s"(c1), "+s"(c2), "+s"(c3), "+s"(cs));

        // dot, dims ascending, accumulator = dim%4 (bit-matches prior rounds)
#define Q4(cv, i4, b, xarr)                                 \
        d0 = fmaf(cv[(i4) * 4 + 0], xarr[(b) * 4 + 0], d0); \
        d1 = fmaf(cv[(i4) * 4 + 1], xarr[(b) * 4 + 1], d1); \
        d2 = fmaf(cv[(i4) * 4 + 2], xarr[(b) * 4 + 2], d2); \
        d3 = fmaf(cv[(i4) * 4 + 3], xarr[(b) * 4 + 3], d3);
        {
            float d0 = 0.f, d1 = 0.f, d2 = 0.f, d3 = 0.f;
            Q4(c0, 0, 0, xrA)  Q4(c0, 1, 1, xrA)  Q4(c0, 2, 2, xrA)  Q4(c0, 3, 3, xrA)
            Q4(c1, 0, 4, xrA)  Q4(c1, 1, 5, xrA)  Q4(c1, 2, 6, xrA)  Q4(c1, 3, 7, xrA)
            Q4(c2, 0, 8, xrA)  Q4(c2, 1, 9, xrA)  Q4(c2, 2, 10, xrA) Q4(c2, 3, 11, xrA)
            Q4(c3, 0, 12, xrA) Q4(c3, 1, 13, xrA) Q4(c3, 2, 14, xrA) Q4(c3, 3, 15, xrA)
            float dot = (d0 + d1) + (d2 + d3);
            float dist = (x_sqA + cs) - 2.0f * dot;
            if (dist < bestA) { bestA = dist; biA = k; }
        }
        {
            float d0 = 0.f, d1 = 0.f, d2 = 0.f, d3 = 0.f;
            Q4(c0, 0, 0, xrB)  Q4(c0, 1, 1, xrB)  Q4(c0, 2, 2, xrB)  Q4(c0, 3, 3, xrB)
            Q4(c1, 0, 4, xrB)  Q4(c1, 1, 5, xrB)  Q4(c1, 2, 6, xrB)  Q4(c1, 3, 7, xrB)
            Q4(c2, 0, 8, xrB)  Q4(c2, 1, 9, xrB)  Q4(c2, 2, 10, xrB) Q4(c2, 3, 11, xrB)
            Q4(c3, 0, 12, xrB) Q4(c3, 1, 13, xrB) Q4(c3, 2, 14, xrB) Q4(c3, 3, 15, xrB)
            float dot = (d0 + d1) + (d2 + d3);
            float dist = (x_sqB + cs) - 2.0f * dot;
            if (dist < bestB) { bestB = dist; biB = k; }
        }
#undef Q4
    }

    // merge the two halves: prefer the lower half on exact ties
    if (kh == 1) {
        m_d[ql] = bestA;       m_i[ql] = biA;
        m_d[128 + ql] = bestB; m_i[128 + ql] = biB;
    }
    __syncthreads();
    if (kh == 0) {
        float dh = m_d[ql];
        int ih = m_i[ql];
        if (dh < bestA) { bestA = dh; biA = ih; }
        m_i[ql] = biA;
        out[IDX_OFF + (size_t)btA * NG + g] = (float)biA;

        float dh2 = m_d[128 + ql];
        int ih2 = m_i[128 + ql];
        if (dh2 < bestB) { bestB = dh2; biB = ih2; }
        m_i[128 + ql] = biB;
        out[IDX_OFF + (size_t)btB * NG + g] = (float)biB;
    }
    __syncthreads();

    // ---- epilogue: coalesced x_q writes + loss partial (r9 pattern, 256 rows) ----
    const int r_off = t >> 4;   // 0..15
    const int c4i = t & 15;     // float4 column
    float s0 = 0.f, s1 = 0.f, s2 = 0.f, s3 = 0.f;
#pragma unroll
    for (int p = 0; p < 16; ++p) {
        const int r = p * 16 + r_off;
        const int code = m_i[r];
        const size_t base = (size_t)(q0 + r) * DIM + g * GD + c4i * 4;
        float4 x4 = *(const float4*)(x + base);
        float4 q4 = *(const float4*)(cbg + (size_t)code * GD + c4i * 4);
        float dx = q4.x - x4.x;
        float dy = q4.y - x4.y;
        float dz = q4.z - x4.z;
        float dw = q4.w - x4.w;
        float4 o;
        o.x = x4.x + dx;
        o.y = x4.y + dy;
        o.z = x4.z + dz;
        o.w = x4.w + dw;
        *(float4*)(out + base) = o;
        s0 = fmaf(dx, dx, s0);
        s1 = fmaf(dy, dy, s1);
        s2 = fmaf(dz, dz, s2);
        s3 = fmaf(dw, dw, s3);
    }
    float part = (s0 + s1) + (s2 + s3);

    // wave reduce (64 lanes)
#pragma unroll
    for (int off = 32; off > 0; off >>= 1) part += __shfl_down(part, off);

    const int lane = t & 63;
    const int wid = t >> 6;
    if (lane == 0) wsum[wid] = part;
    __syncthreads();
    if (t == 0) {
        float bs = (wsum[0] + wsum[1]) + (wsum[2] + wsum[3]);
        // losses = 2 * sum_g mean_{B,T,gd}; divisor = 32768*64 = 2097152
        atomicAdd(out + LOSS_OFF, bs * (2.0f / 2097152.0f));
    }
}

extern "C" void kernel_launch(void* const* d_in, const int* in_sizes, int n_in,
                              void* d_out, int out_size, void* d_ws, size_t ws_size,
                              hipStream_t stream) {
    const float* x = (const float*)d_in[0];
    const float* cb = (const float*)d_in[1];
    float* out = (float*)d_out;
    float* csq = (float*)d_ws;  // 2048 floats = 8 KB scratch

    pq_prep<<<dim3(8), dim3(256), 0, stream>>>(cb, csq, out + LOSS_OFF);

    dim3 grid(BT_TOTAL / QB, NG);   // (128, 8) = 1024 blocks, 4096 waves
    pq_main<<<grid, dim3(256), 0, stream>>>(x, cb, csq, out);
}